// Round 7
// baseline (509.069 us; speedup 1.0000x reference)
//
#include <hip/hip_runtime.h>

#define Bb 2
#define Nn 50000
#define Ee 512000
#define DE 128
#define HH 256
#define DO 128
#define TILES 782        // ceil(50000/64)
#define CAP 48           // per-node edge-list capacity (Poisson(10.24) max deg ~35)
#define NCNT (Bb * Nn)   // 100,000 nodes; cnt[NCNT] is the spill counter
#define SPILL_MAX 65536

typedef __attribute__((ext_vector_type(8))) short short8;
typedef __attribute__((ext_vector_type(4))) float f32x4;

// Agent-scope atomic store: used ONLY to lay down the zeros that later
// kernels' atomicAdds RMW (round-3: plain-stored zeros + cross-kernel atomic
// RMW diverged during graph replay; rounds 4/5 proved this variant safe).
#define ATOMIC_ST(p, v) __hip_atomic_store((p), (v), __ATOMIC_RELAXED, __HIP_MEMORY_SCOPE_AGENT)

// f32 -> bf16 round-to-nearest-even (data has no NaN/Inf)
static __device__ __forceinline__ unsigned short f2bf(float f) {
  union { float f; unsigned int u; } x; x.f = f;
  return (unsigned short)((x.u + 0x7FFFu + ((x.u >> 16) & 1u)) >> 16);
}

// bf16 -> f32 (bit shift; no gfx950 builtin needed)
static __device__ __forceinline__ float bf2f(unsigned short h) {
  union { unsigned int u; float f; } x; x.u = ((unsigned int)h) << 16;
  return x.f;
}

// Pre-convert W1 [256,256] and W2 [256,128] (f32, row-major [k][n]) into
// bf16 MFMA B-fragment order: frag(ct,ks): lane l holds col=ct*16+(l&15),
// k = ks*32+(l>>4)*8+j, j=0..7 contiguous -> one dwordx4 per fragment load.
__global__ void wconv_kernel(const float* __restrict__ W1, const float* __restrict__ W2,
                             unsigned short* __restrict__ w1f, unsigned short* __restrict__ w2f) {
  int t = blockIdx.x * 256 + threadIdx.x;
  if (t < 16 * 8 * 64) {
    int lane = t & 63, ks = (t >> 6) & 7, ct = t >> 9;
    int col = ct * 16 + (lane & 15);
    int k0 = ks * 32 + (lane >> 4) * 8;
    for (int j = 0; j < 8; ++j)
      w1f[t * 8 + j] = f2bf(W1[(k0 + j) * HH + col]);
  }
  if (t < 8 * 8 * 64) {
    int lane = t & 63, ks = (t >> 6) & 7, ct = t >> 9;
    int col = ct * 16 + (lane & 15);
    int k0 = ks * 32 + (lane >> 4) * 8;
    for (int j = 0; j < 8; ++j)
      w2f[t * 8 + j] = f2bf(W2[(k0 + j) * DO + col]);
  }
}

// Zero cnt[0..NCNT] (incl. spill counter) with AGENT-scope atomic stores.
__global__ void zero_cnt_kernel(int* __restrict__ cnt) {
  int i = blockIdx.x * 256 + threadIdx.x;
  if (i <= NCNT) ATOMIC_ST(&cnt[i], 0);
}

// Build per-node edge lists: one int atomic per edge; plain ids stores
// (round-2/5-proven visible to the next dispatch's plain loads).
__global__ void fill_kernel(const int* __restrict__ recv, int* __restrict__ cnt,
                            int* __restrict__ ids, int* __restrict__ spill) {
  int i = blockIdx.x * 256 + threadIdx.x;  // grid sized to exactly Bb*Ee
  if (i >= Bb * Ee) return;
  int b = (i >= Ee) ? 1 : 0;
  int node = b * Nn + recv[i];
  int pos = atomicAdd(&cnt[node], 1);
  if (pos < CAP) {
    ids[(long)node * CAP + pos] = i;  // GLOBAL edge index
  } else {
    int s = atomicAdd(&cnt[NCNT], 1);
    if (s < SPILL_MAX) spill[s] = i;
  }
}

// Fused gather + MLP: per block, 64 nodes.
// Phase A: stage node_data (cols 128..255) into LDS (bf16, XOR-swizzled).
// Phase B: gather edge sums (cols 0..127) straight into LDS — half-wave per
//          node, lane owns a float4 of the row; ids read as int2 so 2 edge
//          loads are in flight per chain step. agg buffer eliminated.
// Then GEMM1 (K=256,N=256) -> relu -> h in LDS -> GEMM2 -> out f32.
__global__ __launch_bounds__(256, 2) void fused_mlp_kernel(
    const float* __restrict__ edge, const float* __restrict__ node,
    const int* __restrict__ cnt, const int* __restrict__ ids,
    const int* __restrict__ spill, const int* __restrict__ recv,
    const unsigned short* __restrict__ w1f, const unsigned short* __restrict__ w2f,
    const float* __restrict__ b1, const float* __restrict__ b2,
    float* __restrict__ out) {
  __shared__ __align__(16) char lds[64 * 512];  // 64 rows x 256 cols bf16
  const int tid = threadIdx.x;
  const int lane = tid & 63;
  const int wv = tid >> 6;
  const int blk = blockIdx.x;
  const int b = blk / TILES;
  const int tile = blk - b * TILES;
  const int row0 = tile * 64;
  const int rows = min(64, Nn - row0);
  const float4* __restrict__ edge4 = reinterpret_cast<const float4*>(edge);

  // ---- Phase A: node features -> LDS cols 128..255 ----
#pragma unroll
  for (int ii = 0; ii < 8; ++ii) {
    int idx = ii * 256 + tid;
    int row = idx >> 5;
    int c4n = idx & 31;  // node float4 col (global col 128 + c4n*4)
    float4 v = make_float4(0.f, 0.f, 0.f, 0.f);
    if (row < rows)
      v = reinterpret_cast<const float4*>(node)[((long)b * Nn + row0 + row) * 32 + c4n];
    ushort4 p;
    p.x = f2bf(v.x); p.y = f2bf(v.y); p.z = f2bf(v.z); p.w = f2bf(v.w);
    int byte = row * 512 + ((256 + c4n * 8) ^ ((row & 7) << 4));
    *reinterpret_cast<ushort4*>(&lds[byte]) = p;
  }

  // ---- Phase B: gather edge sums -> LDS cols 0..127 ----
  {
    const int hw = tid >> 5;   // half-wave 0..7, owns rows k*8+hw
    const int hl = tid & 31;   // lane in half: float4 cols hl*4..hl*4+3
#pragma unroll
    for (int k = 0; k < 8; ++k) {
      int rloc = k * 8 + hw;
      float4 acc = make_float4(0.f, 0.f, 0.f, 0.f);
      if (rloc < rows) {
        int g = b * Nn + row0 + rloc;
        int deg = min(cnt[g], CAP);
        const int2* p2 = reinterpret_cast<const int2*>(ids + (long)g * CAP);
        int npair = (deg + 1) >> 1;
        for (int i = 0; i < npair; ++i) {
          int2 pr = p2[i];
          float4 va = edge4[(long)pr.x * 32 + hl];  // 2*i < deg always
          float4 vb = make_float4(0.f, 0.f, 0.f, 0.f);
          if (2 * i + 1 < deg) vb = edge4[(long)pr.y * 32 + hl];
          acc.x += va.x + vb.x; acc.y += va.y + vb.y;
          acc.z += va.z + vb.z; acc.w += va.w + vb.w;
        }
      }
      ushort4 q;
      q.x = f2bf(acc.x); q.y = f2bf(acc.y); q.z = f2bf(acc.z); q.w = f2bf(acc.w);
      int byte = rloc * 512 + ((hl * 8) ^ ((rloc & 7) << 4));
      *reinterpret_cast<ushort4*>(&lds[byte]) = q;
    }
  }
  __syncthreads();

  // ---- rare spill fix-up (deg > CAP; normally cnt[NCNT]==0) ----
  {
    int sn = min(cnt[NCNT], SPILL_MAX);
    if (sn > 0) {
      const int hw = tid >> 5;
      const int hl = tid & 31;
      for (int k = 0; k < 8; ++k) {
        int rloc = k * 8 + hw;
        if (rloc >= rows) continue;
        int g = b * Nn + row0 + rloc;
        float4 add = make_float4(0.f, 0.f, 0.f, 0.f);
        bool any = false;
        for (int s = 0; s < sn; ++s) {
          int i = spill[s];
          int nb = (i >= Ee) ? 1 : 0;
          if (nb * Nn + recv[i] == g) {
            float4 v = edge4[(long)i * 32 + hl];
            add.x += v.x; add.y += v.y; add.z += v.z; add.w += v.w;
            any = true;
          }
        }
        if (any) {  // bf16 RMW; sole owner (hw,hl) -> no race
          int byte = rloc * 512 + ((hl * 8) ^ ((rloc & 7) << 4));
          ushort4 q = *reinterpret_cast<ushort4*>(&lds[byte]);
          q.x = f2bf(bf2f(q.x) + add.x);
          q.y = f2bf(bf2f(q.y) + add.y);
          q.z = f2bf(bf2f(q.z) + add.z);
          q.w = f2bf(bf2f(q.w) + add.w);
          *reinterpret_cast<ushort4*>(&lds[byte]) = q;
        }
      }
      __syncthreads();  // uniform condition -> legal
    }
  }

  // ---- GEMM1: h = relu(vtin @ W1 + b1) ----
  f32x4 acc[16];
#pragma unroll
  for (int ct = 0; ct < 16; ++ct) acc[ct] = (f32x4){0.f, 0.f, 0.f, 0.f};
  const int arow = wv * 16 + (lane & 15);
  const int abase = arow * 512;
  const int aswz = (arow & 7) << 4;
  const int koff = (lane >> 4) * 16;
#pragma unroll
  for (int ks = 0; ks < 8; ++ks) {
    short8 a = *reinterpret_cast<const short8*>(&lds[abase + ((ks * 64 + koff) ^ aswz)]);
#pragma unroll
    for (int ct = 0; ct < 16; ++ct) {
      short8 bf = *reinterpret_cast<const short8*>(w1f + ((ct * 8 + ks) * 64 + lane) * 8);
      acc[ct] = __builtin_amdgcn_mfma_f32_16x16x32_bf16(a, bf, acc[ct], 0, 0, 0);
    }
  }
  __syncthreads();  // all waves done reading vtin before overwrite

  // ---- bias + relu, write h (bf16, swizzled) ----
  {
    const int colb = lane & 15;
    const int rb = wv * 16 + (lane >> 4) * 4;
#pragma unroll
    for (int ct = 0; ct < 16; ++ct) {
      float bias = b1[ct * 16 + colb];
#pragma unroll
      for (int j = 0; j < 4; ++j) {
        float hv = acc[ct][j] + bias;
        hv = hv > 0.f ? hv : 0.f;
        int row = rb + j;
        int byte = row * 512 + (((ct * 16 + colb) * 2) ^ ((row & 7) << 4));
        *reinterpret_cast<unsigned short*>(&lds[byte]) = f2bf(hv);
      }
    }
  }
  __syncthreads();

  // ---- GEMM2: out = h @ W2 + b2 ----
  f32x4 acc2[8];
#pragma unroll
  for (int ct = 0; ct < 8; ++ct) acc2[ct] = (f32x4){0.f, 0.f, 0.f, 0.f};
#pragma unroll
  for (int ks = 0; ks < 8; ++ks) {
    short8 a = *reinterpret_cast<const short8*>(&lds[abase + ((ks * 64 + koff) ^ aswz)]);
#pragma unroll
    for (int ct = 0; ct < 8; ++ct) {
      short8 bf = *reinterpret_cast<const short8*>(w2f + ((ct * 8 + ks) * 64 + lane) * 8);
      acc2[ct] = __builtin_amdgcn_mfma_f32_16x16x32_bf16(a, bf, acc2[ct], 0, 0, 0);
    }
  }
  {
    const int colb = lane & 15;
    const int rb = wv * 16 + (lane >> 4) * 4;
#pragma unroll
    for (int ct = 0; ct < 8; ++ct) {
      float bias = b2[ct * 16 + colb];
#pragma unroll
      for (int j = 0; j < 4; ++j) {
        int r = rb + j;
        if (r < rows)
          out[((long)b * Nn + row0 + r) * DO + ct * 16 + colb] = acc2[ct][j] + bias;
      }
    }
  }
}

extern "C" void kernel_launch(void* const* d_in, const int* in_sizes, int n_in,
                              void* d_out, int out_size, void* d_ws, size_t ws_size,
                              hipStream_t stream) {
  const float* edge = (const float*)d_in[0];
  const float* node = (const float*)d_in[1];
  const float* W1   = (const float*)d_in[2];
  const float* b1   = (const float*)d_in[3];
  const float* W2   = (const float*)d_in[4];
  const float* b2   = (const float*)d_in[5];
  const int*   recv = (const int*)d_in[6];
  float* out = (float*)d_out;

  char* ws = (char*)d_ws;
  unsigned short* w1f = (unsigned short*)ws;                       // 131,072 B
  unsigned short* w2f = (unsigned short*)(ws + 131072);            //  65,536 B
  int* cnt   = (int*)(ws + 131072 + 65536);                        // (NCNT+1)*4 -> pad 400,016
  int* spill = (int*)(ws + 131072 + 65536 + 400016);               // SPILL_MAX*4 = 262,144
  int* ids   = (int*)(ws + 131072 + 65536 + 400016 + 262144);      // NCNT*CAP*4 = 19,200,000

  wconv_kernel<<<32, 256, 0, stream>>>(W1, W2, w1f, w2f);
  zero_cnt_kernel<<<(NCNT + 256) / 256, 256, 0, stream>>>(cnt);
  fill_kernel<<<Bb * Ee / 256, 256, 0, stream>>>(recv, cnt, ids, spill);
  fused_mlp_kernel<<<Bb * TILES, 256, 0, stream>>>(edge, node, cnt, ids, spill, recv,
                                                   w1f, w2f, b1, b2, out);
}

// Round 8
// 367.948 us; speedup vs baseline: 1.3835x; 1.3835x over previous
//
#include <hip/hip_runtime.h>

#define Bb 2
#define Nn 50000
#define Ee 512000
#define DE 128
#define HH 256
#define DO 128
#define TILES 782        // ceil(50000/64)
#define CAP 48           // per-node edge-list capacity (Poisson(10.24) max deg ~35)
#define NCNT (Bb * Nn)   // 100,000 nodes; cnt[NCNT] is the spill counter
#define SPILL_MAX 65536

typedef __attribute__((ext_vector_type(8))) short short8;
typedef __attribute__((ext_vector_type(4))) float f32x4;

// Agent-scope atomic store: used ONLY to lay down the zeros that later
// kernels' atomicAdds RMW (round-3: plain-stored zeros + cross-kernel atomic
// RMW diverged during graph replay; rounds 4/5 proved this variant safe).
#define ATOMIC_ST(p, v) __hip_atomic_store((p), (v), __ATOMIC_RELAXED, __HIP_MEMORY_SCOPE_AGENT)

// f32 -> bf16 round-to-nearest-even (data has no NaN/Inf)
static __device__ __forceinline__ unsigned short f2bf(float f) {
  union { float f; unsigned int u; } x; x.f = f;
  return (unsigned short)((x.u + 0x7FFFu + ((x.u >> 16) & 1u)) >> 16);
}

// Pre-convert W1 [256,256] and W2 [256,128] (f32, row-major [k][n]) into
// bf16 MFMA B-fragment order: frag(ct,ks): lane l holds col=ct*16+(l&15),
// k = ks*32+(l>>4)*8+j, j=0..7 contiguous -> one dwordx4 per fragment load.
__global__ void wconv_kernel(const float* __restrict__ W1, const float* __restrict__ W2,
                             unsigned short* __restrict__ w1f, unsigned short* __restrict__ w2f) {
  int t = blockIdx.x * 256 + threadIdx.x;
  if (t < 16 * 8 * 64) {
    int lane = t & 63, ks = (t >> 6) & 7, ct = t >> 9;
    int col = ct * 16 + (lane & 15);
    int k0 = ks * 32 + (lane >> 4) * 8;
    for (int j = 0; j < 8; ++j)
      w1f[t * 8 + j] = f2bf(W1[(k0 + j) * HH + col]);
  }
  if (t < 8 * 8 * 64) {
    int lane = t & 63, ks = (t >> 6) & 7, ct = t >> 9;
    int col = ct * 16 + (lane & 15);
    int k0 = ks * 32 + (lane >> 4) * 8;
    for (int j = 0; j < 8; ++j)
      w2f[t * 8 + j] = f2bf(W2[(k0 + j) * DO + col]);
  }
}

// Zero cnt[0..NCNT] (incl. spill counter) with AGENT-scope atomic stores.
__global__ void zero_cnt_kernel(int* __restrict__ cnt) {
  int i = blockIdx.x * 256 + threadIdx.x;
  if (i <= NCNT) ATOMIC_ST(&cnt[i], 0);
}

// Build per-node edge lists: one int atomic per edge; plain ids stores
// (round-2/5-proven visible to the next dispatch's plain loads).
__global__ void fill_kernel(const int* __restrict__ recv, int* __restrict__ cnt,
                            int* __restrict__ ids, int* __restrict__ spill) {
  int i = blockIdx.x * 256 + threadIdx.x;  // grid sized to exactly Bb*Ee
  if (i >= Bb * Ee) return;
  int b = (i >= Ee) ? 1 : 0;
  int node = b * Nn + recv[i];
  int pos = atomicAdd(&cnt[node], 1);
  if (pos < CAP) {
    ids[(long)node * CAP + pos] = i;  // GLOBAL edge index
  } else {
    int s = atomicAdd(&cnt[NCNT], 1);
    if (s < SPILL_MAX) spill[s] = i;
  }
}

// Gather-sum with max memory-level parallelism: ONE HALF-WAVE PER NODE,
// lane hl owns float4 cols hl*4..hl*4+3. ids read as int4 -> 4 independent
// 512B edge-row loads in flight per chain step. No LDS; high occupancy
// (launch_bounds caps VGPR so ~8 waves/SIMD). Round-7 post-mortem: the fused
// version idled at 715 GB/s because occupancy*ILP gave only ~1.5MB in flight.
// Output agg in BF16 (halves agg traffic; MLP consumes bf16 directly).
__global__ __launch_bounds__(256, 8) void gather_kernel(
    const float4* __restrict__ edge4, const int* __restrict__ cnt,
    const int* __restrict__ ids, const int* __restrict__ spill,
    const int* __restrict__ recv, unsigned short* __restrict__ aggb) {
  int half = (blockIdx.x * 256 + threadIdx.x) >> 5;  // global half-wave = node id
  int hl = threadIdx.x & 31;
  if (half >= NCNT) return;
  const int g = half;
  int deg0 = cnt[g];
  int deg = min(deg0, CAP);
  const int4* p4 = reinterpret_cast<const int4*>(ids + (long)g * CAP);
  float4 acc = make_float4(0.f, 0.f, 0.f, 0.f);

  int nfull = deg >> 2;
  for (int i = 0; i < nfull; ++i) {
    int4 q = p4[i];
    float4 v0 = edge4[(long)q.x * 32 + hl];
    float4 v1 = edge4[(long)q.y * 32 + hl];
    float4 v2 = edge4[(long)q.z * 32 + hl];
    float4 v3 = edge4[(long)q.w * 32 + hl];
    acc.x += (v0.x + v1.x) + (v2.x + v3.x);
    acc.y += (v0.y + v1.y) + (v2.y + v3.y);
    acc.z += (v0.z + v1.z) + (v2.z + v3.z);
    acc.w += (v0.w + v1.w) + (v2.w + v3.w);
  }
  int rem = deg & 3;
  if (rem) {
    int4 q = p4[nfull];
    float4 v0 = edge4[(long)q.x * 32 + hl];
    acc.x += v0.x; acc.y += v0.y; acc.z += v0.z; acc.w += v0.w;
    if (rem > 1) {
      float4 v1 = edge4[(long)q.y * 32 + hl];
      acc.x += v1.x; acc.y += v1.y; acc.z += v1.z; acc.w += v1.w;
    }
    if (rem > 2) {
      float4 v2 = edge4[(long)q.z * 32 + hl];
      acc.x += v2.x; acc.y += v2.y; acc.z += v2.z; acc.w += v2.w;
    }
  }
  // rare overflow: this node's extra edges sit in the spill list
  if (deg0 > CAP) {
    int sn = min(cnt[NCNT], SPILL_MAX);
    for (int s = 0; s < sn; ++s) {
      int e = spill[s];
      int nb = (e >= Ee) ? 1 : 0;
      if (nb * Nn + recv[e] == g) {
        float4 v = edge4[(long)e * 32 + hl];
        acc.x += v.x; acc.y += v.y; acc.z += v.z; acc.w += v.w;
      }
    }
  }
  ushort4 o;
  o.x = f2bf(acc.x); o.y = f2bf(acc.y); o.z = f2bf(acc.z); o.w = f2bf(acc.w);
  reinterpret_cast<ushort4*>(aggb)[(long)g * 32 + hl] = o;
}

// MLP: per block, 64 nodes. vtin=[aggb(bf16)|node(f32->bf16)] in LDS
// (XOR-swizzled), GEMM1 (K=256,N=256) -> relu -> h in LDS -> GEMM2 -> out.
// 4 waves; wave w owns rows w*16..w*16+15. B-operands from pre-fragmented ws.
__global__ __launch_bounds__(256, 2) void mlp_kernel(
    const unsigned short* __restrict__ aggb, const float* __restrict__ node,
    const unsigned short* __restrict__ w1f, const unsigned short* __restrict__ w2f,
    const float* __restrict__ b1, const float* __restrict__ b2,
    float* __restrict__ out) {
  __shared__ __align__(16) char lds[64 * 512];  // 64 rows x 256 cols bf16
  const int tid = threadIdx.x;
  const int lane = tid & 63;
  const int wv = tid >> 6;
  const int blk = blockIdx.x;
  const int b = blk / TILES;
  const int tile = blk - b * TILES;
  const int row0 = tile * 64;
  const int rows = min(64, Nn - row0);

  // ---- stage vtin: agg half is already bf16; node half converts ----
#pragma unroll
  for (int ii = 0; ii < 8; ++ii) {  // cols 0..127 from aggb
    int idx = ii * 256 + tid;
    int row = idx >> 5;
    int c4 = idx & 31;
    ushort4 p = make_ushort4(0, 0, 0, 0);
    if (row < rows)
      p = reinterpret_cast<const ushort4*>(aggb)[((long)b * Nn + row0 + row) * 32 + c4];
    int byte = row * 512 + ((c4 * 8) ^ ((row & 7) << 4));
    *reinterpret_cast<ushort4*>(&lds[byte]) = p;
  }
#pragma unroll
  for (int ii = 0; ii < 8; ++ii) {  // cols 128..255 from node_data
    int idx = ii * 256 + tid;
    int row = idx >> 5;
    int c4 = idx & 31;
    float4 v = make_float4(0.f, 0.f, 0.f, 0.f);
    if (row < rows)
      v = reinterpret_cast<const float4*>(node)[((long)b * Nn + row0 + row) * 32 + c4];
    ushort4 p;
    p.x = f2bf(v.x); p.y = f2bf(v.y); p.z = f2bf(v.z); p.w = f2bf(v.w);
    int byte = row * 512 + ((256 + c4 * 8) ^ ((row & 7) << 4));
    *reinterpret_cast<ushort4*>(&lds[byte]) = p;
  }
  __syncthreads();

  // ---- GEMM1: h = relu(vtin @ W1 + b1) ----
  f32x4 acc[16];
#pragma unroll
  for (int ct = 0; ct < 16; ++ct) acc[ct] = (f32x4){0.f, 0.f, 0.f, 0.f};
  const int arow = wv * 16 + (lane & 15);
  const int abase = arow * 512;
  const int aswz = (arow & 7) << 4;
  const int koff = (lane >> 4) * 16;
#pragma unroll
  for (int ks = 0; ks < 8; ++ks) {
    short8 a = *reinterpret_cast<const short8*>(&lds[abase + ((ks * 64 + koff) ^ aswz)]);
#pragma unroll
    for (int ct = 0; ct < 16; ++ct) {
      short8 bf = *reinterpret_cast<const short8*>(w1f + ((ct * 8 + ks) * 64 + lane) * 8);
      acc[ct] = __builtin_amdgcn_mfma_f32_16x16x32_bf16(a, bf, acc[ct], 0, 0, 0);
    }
  }
  __syncthreads();  // all waves done reading vtin before overwrite

  // ---- bias + relu, write h (bf16, swizzled) ----
  {
    const int colb = lane & 15;
    const int rb = wv * 16 + (lane >> 4) * 4;
#pragma unroll
    for (int ct = 0; ct < 16; ++ct) {
      float bias = b1[ct * 16 + colb];
#pragma unroll
      for (int j = 0; j < 4; ++j) {
        float hv = acc[ct][j] + bias;
        hv = hv > 0.f ? hv : 0.f;
        int row = rb + j;
        int byte = row * 512 + (((ct * 16 + colb) * 2) ^ ((row & 7) << 4));
        *reinterpret_cast<unsigned short*>(&lds[byte]) = f2bf(hv);
      }
    }
  }
  __syncthreads();

  // ---- GEMM2: out = h @ W2 + b2 ----
  f32x4 acc2[8];
#pragma unroll
  for (int ct = 0; ct < 8; ++ct) acc2[ct] = (f32x4){0.f, 0.f, 0.f, 0.f};
#pragma unroll
  for (int ks = 0; ks < 8; ++ks) {
    short8 a = *reinterpret_cast<const short8*>(&lds[abase + ((ks * 64 + koff) ^ aswz)]);
#pragma unroll
    for (int ct = 0; ct < 8; ++ct) {
      short8 bf = *reinterpret_cast<const short8*>(w2f + ((ct * 8 + ks) * 64 + lane) * 8);
      acc2[ct] = __builtin_amdgcn_mfma_f32_16x16x32_bf16(a, bf, acc2[ct], 0, 0, 0);
    }
  }
  {
    const int colb = lane & 15;
    const int rb = wv * 16 + (lane >> 4) * 4;
#pragma unroll
    for (int ct = 0; ct < 8; ++ct) {
      float bias = b2[ct * 16 + colb];
#pragma unroll
      for (int j = 0; j < 4; ++j) {
        int r = rb + j;
        if (r < rows)
          out[((long)b * Nn + row0 + r) * DO + ct * 16 + colb] = acc2[ct][j] + bias;
      }
    }
  }
}

extern "C" void kernel_launch(void* const* d_in, const int* in_sizes, int n_in,
                              void* d_out, int out_size, void* d_ws, size_t ws_size,
                              hipStream_t stream) {
  const float* edge = (const float*)d_in[0];
  const float* node = (const float*)d_in[1];
  const float* W1   = (const float*)d_in[2];
  const float* b1   = (const float*)d_in[3];
  const float* W2   = (const float*)d_in[4];
  const float* b2   = (const float*)d_in[5];
  const int*   recv = (const int*)d_in[6];
  float* out = (float*)d_out;

  char* ws = (char*)d_ws;
  size_t off = 0;
  unsigned short* w1f = (unsigned short*)(ws + off); off += 131072;
  unsigned short* w2f = (unsigned short*)(ws + off); off += 65536;
  int* cnt   = (int*)(ws + off); off += 400016;                 // (NCNT+1)*4 padded
  int* spill = (int*)(ws + off); off += SPILL_MAX * 4;          // 262,144
  int* ids   = (int*)(ws + off); off += (size_t)NCNT * CAP * 4; // 19,200,000
  unsigned short* aggb = (unsigned short*)(ws + off);           // NCNT*128*2 = 25,600,000

  wconv_kernel<<<32, 256, 0, stream>>>(W1, W2, w1f, w2f);
  zero_cnt_kernel<<<(NCNT + 256) / 256, 256, 0, stream>>>(cnt);
  fill_kernel<<<Bb * Ee / 256, 256, 0, stream>>>(recv, cnt, ids, spill);
  gather_kernel<<<NCNT / 8, 256, 0, stream>>>((const float4*)edge, cnt, ids, spill, recv, aggb);
  mlp_kernel<<<Bb * TILES, 256, 0, stream>>>(aggb, node, w1f, w2f, b1, b2, out);
}